// Round 17
// baseline (335.667 us; speedup 1.0000x reference)
//
#include <hip/hip_runtime.h>
#include <hip/hip_fp16.h>
#include <hip/hip_fp8.h>
#include <math.h>

#define N_NODES 50000
#define N_EDGES 1200000
#define N_GRAPHS 128
#define D_IN 32
#define D_H 64
#define D_OUT 10
#define ELL_CAP 64

#define EPS 1e-7f
#define MAX_NORM (1.0f - 1e-5f)
// atanh(MAX_NORM): logmap0(proj(expmap0(m))) == m * min(1, TCLIP/||m||)
#define TCLIP 6.1030335f
#define T8SCALE 16.0f            // fp8 table pre-scale (folded into mean div)

typedef _Float16 half8 __attribute__((ext_vector_type(8)));
typedef float float4v __attribute__((ext_vector_type(4)));

// ---------------- wave helpers ----------------

__device__ __forceinline__ float wave_reduce_sum(float v) {
    #pragma unroll
    for (int off = 32; off > 0; off >>= 1)
        v += __shfl_xor(v, off, 64);
    return v;
}

// logmap0(proj(expmap0(m))) collapsed to a norm clip (one reduction).
__device__ __forceinline__ float epl_clip64(float m) {
    float n = sqrtf(wave_reduce_sum(m * m));
    float sc = (n > TCLIP) ? (TCLIP / n) : 1.0f;
    return m * sc;
}

// four packed OCP e4m3 bytes -> four floats (gfx950 HW cvt)
__device__ __forceinline__ float4 fp8x4_to_f4(unsigned int w) {
    __hip_fp8_e4m3 a, b, c, d;
    a.__x = (__hip_fp8_storage_t)(w & 0xff);
    b.__x = (__hip_fp8_storage_t)((w >> 8) & 0xff);
    c.__x = (__hip_fp8_storage_t)((w >> 16) & 0xff);
    d.__x = (__hip_fp8_storage_t)(w >> 24);
    return make_float4((float)a, (float)b, (float)c, (float)d);
}

// ---------------- kernels ----------------

// Fused build: [blocks 0..EB) ELL build, one edge per thread; [EB..):
// tangent0 = fp16(clip(x)).
#define EB ((N_EDGES + 255) / 256)
__global__ void build_kernel(const int* __restrict__ src, const int* __restrict__ dst,
                             int* __restrict__ deg, ushort* __restrict__ ell,
                             const float* __restrict__ x, __half* __restrict__ u0) {
    if (blockIdx.x < EB) {
        int e = blockIdx.x * 256 + threadIdx.x;
        if (e < N_EDGES) {
            int s = src[e];
            int d = dst[e];
            s = min(max(s, 0), N_NODES - 1);
            d = min(max(d, 0), N_NODES - 1);
            int pos = atomicAdd(&deg[d], 1);
            if (pos < ELL_CAP) ell[d * ELL_CAP + pos] = (ushort)s;
        }
    } else {
        int gid = (blockIdx.x - EB) * 256 + threadIdx.x;
        int node = gid >> 6;
        int lane = gid & 63;
        if (node >= N_NODES) return;
        float m = (lane < D_IN) ? x[node * D_IN + lane] : 0.0f;
        float t = epl_clip64(m);
        if (lane < D_IN) u0[node * D_IN + lane] = __float2half(t);
    }
}

// Repack W (f32 [K,64]) into B-fragment order for mfma_f32_16x16x32_f16.
template <int K>
__global__ void repack_kernel(const float* __restrict__ W, __half* __restrict__ Whf) {
    const int NF = K / 32;
    int idx = blockIdx.x * 256 + threadIdx.x;
    if (idx >= 4 * NF * 64 * 8) return;
    int j = idx & 7;
    int lane = (idx >> 3) & 63;
    int f = (idx >> 9) % NF;
    int jb = (idx >> 9) / NF;
    int k = f * 32 + ((lane >> 4) * 8) + j;
    int n = jb * 16 + (lane & 15);
    Whf[idx] = __float2half(W[k * 64 + n]);
}

// LAYER 1 pass A: gather-mean of u0 rows (32-dim fp16, 64B = 1 line/edge,
// 3.2MB L2-resident). Quad-per-edge, 4 edges per wave-load.
__global__ void meangather_kernel(const __half* __restrict__ u0, const int* __restrict__ deg,
                                  const ushort* __restrict__ ell, __half* __restrict__ m0) {
    int widx = threadIdx.x >> 6;
    int lane = threadIdx.x & 63;
    int node = blockIdx.x * 4 + widx;
    if (node >= N_NODES) return;
    int quad = lane >> 4;
    int p = lane & 15;                 // dim pair 2p, 2p+1
    int dt = deg[node];
    int d = min(dt, ELL_CAP);
    int id = (lane < d) ? (int)ell[node * ELL_CAP + lane] : 0;
    const __half2* u2 = (const __half2*)u0;   // row stride 16 half2

    float ax = 0.f, ay = 0.f;
    int e = 0;
    for (; e + 16 <= d; e += 16) {     // 16 edges, 4 loads in flight
        int sA0 = __shfl(id, e,      64), sB0 = __shfl(id, e + 1,  64);
        int sC0 = __shfl(id, e + 2,  64), sD0 = __shfl(id, e + 3,  64);
        int sA1 = __shfl(id, e + 4,  64), sB1 = __shfl(id, e + 5,  64);
        int sC1 = __shfl(id, e + 6,  64), sD1 = __shfl(id, e + 7,  64);
        int sA2 = __shfl(id, e + 8,  64), sB2 = __shfl(id, e + 9,  64);
        int sC2 = __shfl(id, e + 10, 64), sD2 = __shfl(id, e + 11, 64);
        int sA3 = __shfl(id, e + 12, 64), sB3 = __shfl(id, e + 13, 64);
        int sC3 = __shfl(id, e + 14, 64), sD3 = __shfl(id, e + 15, 64);
        int t0 = (quad & 1) ? sB0 : sA0, v0 = (quad & 1) ? sD0 : sC0;
        int t1 = (quad & 1) ? sB1 : sA1, v1 = (quad & 1) ? sD1 : sC1;
        int t2_ = (quad & 1) ? sB2 : sA2, v2 = (quad & 1) ? sD2 : sC2;
        int t3 = (quad & 1) ? sB3 : sA3, v3 = (quad & 1) ? sD3 : sC3;
        int s0 = (quad & 2) ? v0 : t0;
        int s1 = (quad & 2) ? v1 : t1;
        int s2 = (quad & 2) ? v2 : t2_;
        int s3 = (quad & 2) ? v3 : t3;
        float2 f0 = __half22float2(u2[s0 * 16 + p]);
        float2 f1 = __half22float2(u2[s1 * 16 + p]);
        float2 f2 = __half22float2(u2[s2 * 16 + p]);
        float2 f3 = __half22float2(u2[s3 * 16 + p]);
        ax += (f0.x + f1.x) + (f2.x + f3.x);
        ay += (f0.y + f1.y) + (f2.y + f3.y);
    }
    if (e + 4 <= d) {
        do {
            int sA = __shfl(id, e, 64), sB = __shfl(id, e + 1, 64);
            int sC = __shfl(id, e + 2, 64), sD = __shfl(id, e + 3, 64);
            int tt = (quad & 1) ? sB : sA, vv = (quad & 1) ? sD : sC;
            int s = (quad & 2) ? vv : tt;
            float2 f = __half22float2(u2[s * 16 + p]);
            ax += f.x; ay += f.y;
            e += 4;
        } while (e + 4 <= d);
    }
    for (; e < d; ++e) {
        int s = __shfl(id, e, 64);
        if (quad == 0) {
            float2 f = __half22float2(u2[s * 16 + p]);
            ax += f.x; ay += f.y;
        }
    }
    ax += __shfl_xor(ax, 16, 64); ax += __shfl_xor(ax, 32, 64);
    ay += __shfl_xor(ay, 16, 64); ay += __shfl_xor(ay, 32, 64);

    float inv = 1.0f / fmaxf((float)dt, 1.0f);
    if (quad == 0)
        ((__half2*)m0)[node * 16 + p] = __floats2half2_rn(ax * inv, ay * inv);
}

// LAYER 1 pass B: u1 = clip(lrelu(m0@W1 + b1)), deg==0 -> 0.
__global__ void gemmepi_kernel(const __half* __restrict__ m0, const __half* __restrict__ Whf,
                               const float* __restrict__ b, const int* __restrict__ deg,
                               __half* __restrict__ uout) {
    int gw = blockIdx.x * 4 + (threadIdx.x >> 6);
    int lane = threadIdx.x & 63;
    int node0 = gw * 16;
    if (node0 >= N_NODES) return;
    int m = lane & 15, quad = lane >> 4;

    half8 a = *(const half8*)(m0 + (size_t)(node0 + m) * 32 + quad * 8);
    float h[4][4];   // [jb][r]
    #pragma unroll
    for (int jb = 0; jb < 4; ++jb) {
        float4v acc = {0.f, 0.f, 0.f, 0.f};
        half8 bb = ((const half8*)Whf)[jb * 64 + lane];
        acc = __builtin_amdgcn_mfma_f32_16x16x32_f16(a, bb, acc, 0, 0, 0);
        float bias = b[jb * 16 + m];
        #pragma unroll
        for (int r = 0; r < 4; ++r) h[jb][r] = acc[r] + bias;
    }
    #pragma unroll
    for (int r = 0; r < 4; ++r) {
        int node = node0 + quad * 4 + r;   // C/D: col=lane&15, row=quad*4+reg
        int dt = deg[node];
        float nr = 0.f;
        #pragma unroll
        for (int jb = 0; jb < 4; ++jb) {
            float v = (dt == 0) ? 0.f : h[jb][r];
            v = (v >= 0.f) ? v : 0.2f * v;   // leaky_relu (layer 1)
            h[jb][r] = v;
            nr += v * v;
        }
        nr += __shfl_xor(nr, 1, 64); nr += __shfl_xor(nr, 2, 64);
        nr += __shfl_xor(nr, 4, 64); nr += __shfl_xor(nr, 8, 64);
        float n = sqrtf(nr);
        float sc = (n > TCLIP) ? (TCLIP / n) : 1.0f;
        #pragma unroll
        for (int jb = 0; jb < 4; ++jb)
            uout[node * 64 + jb * 16 + m] = __float2half(h[jb][r] * sc);
    }
}

// t[N,64] fp8 e4m3 (x16 scale) = u[N,K] fp16 @ W + b via MFMA (layers 2,3).
template <int K>
__global__ void gemm_kernel(const __half* __restrict__ u, const __half* __restrict__ Whf,
                            const float* __restrict__ b, __hip_fp8_e4m3* __restrict__ t8) {
    const int NF = K / 32;
    int gw = blockIdx.x * 4 + (threadIdx.x >> 6);
    int lane = threadIdx.x & 63;
    int jb = gw & 3;
    int tile = gw >> 2;
    int node0 = tile * 16;
    if (node0 >= N_NODES) return;
    int m = lane & 15, quad = lane >> 4;

    float4v acc = {0.f, 0.f, 0.f, 0.f};
    const half8* bfr = (const half8*)Whf + (size_t)(jb * NF) * 64 + lane;
    #pragma unroll
    for (int f = 0; f < NF; ++f) {
        half8 a = *(const half8*)(u + (size_t)(node0 + m) * K + f * 32 + quad * 8);
        half8 bb = bfr[f * 64];
        acc = __builtin_amdgcn_mfma_f32_16x16x32_f16(a, bb, acc, 0, 0, 0);
    }
    int j = jb * 16 + m;
    float bias = b[j];
    #pragma unroll
    for (int r = 0; r < 4; ++r) {
        int node = node0 + quad * 4 + r;
        t8[node * 64 + j] = __hip_fp8_e4m3((acc[r] + bias) * T8SCALE);
    }
}

// Gather-mean over ELL (fp8 rows, 64B): QUAD-PER-EDGE — one wave-load (64
// lanes x 4B uint = 4 packed e4m3) covers FOUR edges (R17: cost tracks
// load-instruction count, not lines — meangather calibration). Lane owns
// dims 4p..4p+3. 16 edges = 4 loads in flight. Then act -> norm-clip ->
// fp16 store, or (POOL) block LDS combine + 1 atomic burst per block.
template <int ACT, int POOL>
__global__ void agg_kernel(const __hip_fp8_e4m3* __restrict__ t8, const int* __restrict__ deg,
                           const ushort* __restrict__ ell, __half* __restrict__ uout,
                           const int* __restrict__ batch, float* __restrict__ pooled,
                           float* __restrict__ cntg) {
    __shared__ float rs[4][64];
    __shared__ int gs[4];
    int widx = threadIdx.x >> 6;
    int lane = threadIdx.x & 63;
    int node = blockIdx.x * 4 + widx;
    if (node >= N_NODES) return;   // never taken when POOL (50000 % 4 == 0)
    int quad = lane >> 4;
    int p = lane & 15;             // dim group 4p..4p+3
    int dt = deg[node];
    int d = min(dt, ELL_CAP);
    int id = (lane < d) ? (int)ell[node * ELL_CAP + lane] : 0;
    const unsigned int* tu = (const unsigned int*)t8;   // row stride 16 uints

    float a0 = 0.f, a1 = 0.f, a2 = 0.f, a3 = 0.f;
    int e = 0;
    for (; e + 16 <= d; e += 16) {     // 16 edges, 4 loads in flight
        int sA0 = __shfl(id, e,      64), sB0 = __shfl(id, e + 1,  64);
        int sC0 = __shfl(id, e + 2,  64), sD0 = __shfl(id, e + 3,  64);
        int sA1 = __shfl(id, e + 4,  64), sB1 = __shfl(id, e + 5,  64);
        int sC1 = __shfl(id, e + 6,  64), sD1 = __shfl(id, e + 7,  64);
        int sA2 = __shfl(id, e + 8,  64), sB2 = __shfl(id, e + 9,  64);
        int sC2 = __shfl(id, e + 10, 64), sD2 = __shfl(id, e + 11, 64);
        int sA3 = __shfl(id, e + 12, 64), sB3 = __shfl(id, e + 13, 64);
        int sC3 = __shfl(id, e + 14, 64), sD3 = __shfl(id, e + 15, 64);
        int t0 = (quad & 1) ? sB0 : sA0, v0 = (quad & 1) ? sD0 : sC0;
        int t1 = (quad & 1) ? sB1 : sA1, v1 = (quad & 1) ? sD1 : sC1;
        int t2_ = (quad & 1) ? sB2 : sA2, v2 = (quad & 1) ? sD2 : sC2;
        int t3 = (quad & 1) ? sB3 : sA3, v3 = (quad & 1) ? sD3 : sC3;
        int s0 = (quad & 2) ? v0 : t0;
        int s1 = (quad & 2) ? v1 : t1;
        int s2 = (quad & 2) ? v2 : t2_;
        int s3 = (quad & 2) ? v3 : t3;
        unsigned int w0 = tu[s0 * 16 + p];
        unsigned int w1 = tu[s1 * 16 + p];
        unsigned int w2 = tu[s2 * 16 + p];
        unsigned int w3 = tu[s3 * 16 + p];
        float4 f0 = fp8x4_to_f4(w0);
        float4 f1 = fp8x4_to_f4(w1);
        float4 f2 = fp8x4_to_f4(w2);
        float4 f3 = fp8x4_to_f4(w3);
        a0 += (f0.x + f1.x) + (f2.x + f3.x);
        a1 += (f0.y + f1.y) + (f2.y + f3.y);
        a2 += (f0.z + f1.z) + (f2.z + f3.z);
        a3 += (f0.w + f1.w) + (f2.w + f3.w);
    }
    while (e + 4 <= d) {               // 4-edge batches
        int sA = __shfl(id, e, 64), sB = __shfl(id, e + 1, 64);
        int sC = __shfl(id, e + 2, 64), sD = __shfl(id, e + 3, 64);
        int tt = (quad & 1) ? sB : sA, vv = (quad & 1) ? sD : sC;
        int s = (quad & 2) ? vv : tt;
        float4 f = fp8x4_to_f4(tu[s * 16 + p]);
        a0 += f.x; a1 += f.y; a2 += f.z; a3 += f.w;
        e += 4;
    }
    for (; e < d; ++e) {               // tail: quad 0 only
        int s = __shfl(id, e, 64);
        if (quad == 0) {
            float4 f = fp8x4_to_f4(tu[s * 16 + p]);
            a0 += f.x; a1 += f.y; a2 += f.z; a3 += f.w;
        }
    }
    // combine quads: every lane ends with full per-dim sums (replicated)
    a0 += __shfl_xor(a0, 16, 64); a0 += __shfl_xor(a0, 32, 64);
    a1 += __shfl_xor(a1, 16, 64); a1 += __shfl_xor(a1, 32, 64);
    a2 += __shfl_xor(a2, 16, 64); a2 += __shfl_xor(a2, 32, 64);
    a3 += __shfl_xor(a3, 16, 64); a3 += __shfl_xor(a3, 32, 64);

    // mean; /T8SCALE undoes the fp8 table pre-scale
    float inv = 1.0f / (T8SCALE * fmaxf((float)dt, 1.0f));
    float m0 = a0 * inv, m1 = a1 * inv, m2 = a2 * inv, m3 = a3 * inv;
    if (ACT) {
        m0 = (m0 >= 0.f) ? m0 : 0.2f * m0;
        m1 = (m1 >= 0.f) ? m1 : 0.2f * m1;
        m2 = (m2 >= 0.f) ? m2 : 0.2f * m2;
        m3 = (m3 >= 0.f) ? m3 : 0.2f * m3;
    }
    // norm over 64 dims: per-lane partial (4 dims) + reduce over p (16)
    float nr = m0 * m0 + m1 * m1 + m2 * m2 + m3 * m3;
    nr += __shfl_xor(nr, 1, 64); nr += __shfl_xor(nr, 2, 64);
    nr += __shfl_xor(nr, 4, 64); nr += __shfl_xor(nr, 8, 64);
    float n = sqrtf(nr);
    float sc = (n > TCLIP) ? (TCLIP / n) : 1.0f;
    m0 *= sc; m1 *= sc; m2 *= sc; m3 *= sc;

    if (POOL) {
        int g = min(max(batch[node], 0), N_GRAPHS - 1);
        if (quad == 0) {
            rs[widx][4 * p]     = m0;
            rs[widx][4 * p + 1] = m1;
            rs[widx][4 * p + 2] = m2;
            rs[widx][4 * p + 3] = m3;
        }
        if (lane == 0) gs[widx] = g;
        __syncthreads();
        int g0 = gs[0], g1 = gs[1], g2 = gs[2], g3 = gs[3];
        bool uni = (g0 == g1) && (g1 == g2) && (g2 == g3);
        if (uni) {
            // sorted batch -> ~99% of blocks: one 64-lane burst per block
            if (widx == 0) {
                float sum = rs[0][lane] + rs[1][lane] + rs[2][lane] + rs[3][lane];
                atomicAdd(&pooled[g0 * 64 + lane], sum);
                if (lane == 0) atomicAdd(&cntg[g0], 4.0f);
            }
        } else {
            if (quad == 0) {
                atomicAdd(&pooled[g * 64 + 4 * p],     m0);
                atomicAdd(&pooled[g * 64 + 4 * p + 1], m1);
                atomicAdd(&pooled[g * 64 + 4 * p + 2], m2);
                atomicAdd(&pooled[g * 64 + 4 * p + 3], m3);
            }
            if (lane == 0) atomicAdd(&cntg[g], 1.0f);
        }
    } else {
        if (quad == 0) {
            __half2* o2 = (__half2*)(uout + (size_t)node * 64 + 4 * p);
            o2[0] = __floats2half2_rn(m0, m1);
            o2[1] = __floats2half2_rn(m2, m3);
        }
    }
}

// final head: mean -> clip -> @Wl + bl -> expmap0 -> proj (literal output)
__global__ void head_kernel(const float* __restrict__ pooled, const float* __restrict__ cntg,
                            const float* __restrict__ Wl, const float* __restrict__ bl,
                            float* __restrict__ out) {
    int g = blockIdx.x;
    int lane = threadIdx.x;
    float m = pooled[g * 64 + lane] / fmaxf(cntg[g], 1.0f);
    float z = epl_clip64(m);
    float acc = 0.0f;
    #pragma unroll
    for (int k = 0; k < 64; ++k) {
        float zk = __shfl(z, k, 64);
        if (lane < D_OUT) acc = fmaf(zk, Wl[k * D_OUT + lane], acc);
    }
    float o = (lane < D_OUT) ? (acc + bl[lane]) : 0.0f;
    float n = fmaxf(sqrtf(wave_reduce_sum(o * o)), EPS);
    float v = tanhf(n) * o / n;
    float nv = fmaxf(sqrtf(wave_reduce_sum(v * v)), EPS);
    if (nv > MAX_NORM) v = v * (MAX_NORM / nv);
    if (lane < D_OUT) out[g * D_OUT + lane] = v;
}

// ---------------- launch ----------------

extern "C" void kernel_launch(void* const* d_in, const int* in_sizes, int n_in,
                              void* d_out, int out_size, void* d_ws, size_t ws_size,
                              hipStream_t stream) {
    const float* x   = (const float*)d_in[0];
    const int* edge  = (const int*)d_in[1];
    const int* batch = (const int*)d_in[2];
    const float* W1  = (const float*)d_in[3];
    const float* b1  = (const float*)d_in[4];
    const float* W2  = (const float*)d_in[5];
    const float* b2  = (const float*)d_in[6];
    const float* W3  = (const float*)d_in[7];
    const float* b3  = (const float*)d_in[8];
    const float* Wl  = (const float*)d_in[9];
    const float* bl  = (const float*)d_in[10];
    float* out = (float*)d_out;

    const int N = N_NODES, E = N_EDGES, G = N_GRAPHS;
    const int* src = edge;
    const int* dst = edge + E;

    // ws layout: [deg][pooled][cntg][ell][u0h N*32 h][u1h N*64 h][u2h N*64 h]
    //            [t8 N*64 fp8][m0h N*32 h][Wh1][Wh2][Wh3]
    char* ws = (char*)d_ws;
    int*    deg    = (int*)ws;
    float*  pooled = (float*)(deg + N);
    float*  cntg   = pooled + (size_t)G * 64;
    ushort* ell    = (ushort*)(cntg + G);
    __half* u0h    = (__half*)(ell + (size_t)N * ELL_CAP);
    __half* u1h    = u0h + (size_t)N * 32;
    __half* u2h    = u1h + (size_t)N * 64;
    __hip_fp8_e4m3* t8 = (__hip_fp8_e4m3*)(u2h + (size_t)N * 64);
    __half* m0h    = (__half*)((char*)t8 + (size_t)N * 64);
    __half* Wh1    = m0h + (size_t)N * 32;    // 2048
    __half* Wh2    = Wh1 + 2048;              // 4096
    __half* Wh3    = Wh2 + 4096;              // 4096

    size_t zero_bytes = ((size_t)N + (size_t)G * 64 + G) * 4;
    hipMemsetAsync(d_ws, 0, zero_bytes, stream);

    int blocksN64 = (N * 64 + 255) / 256;   // one wave per node, 4 per block
    int blocksB   = EB + blocksN64;
    int blocksG   = 3125;                   // layers 2,3 gemm (jb split)
    int blocksT   = (3125 + 3) / 4;         // gemmepi: one wave per 16-node tile

    repack_kernel<32><<<8,  256, 0, stream>>>(W1, Wh1);
    repack_kernel<64><<<16, 256, 0, stream>>>(W2, Wh2);
    repack_kernel<64><<<16, 256, 0, stream>>>(W3, Wh3);
    build_kernel<<<blocksB, 256, 0, stream>>>(src, dst, deg, ell, x, u0h);

    // layer 1: gather-mean u0 (L2-resident, 1 line/edge) -> MFMA+epi
    meangather_kernel<<<blocksN64, 256, 0, stream>>>(u0h, deg, ell, m0h);
    gemmepi_kernel<<<blocksT, 256, 0, stream>>>(m0h, Wh1, b1, deg, u1h);

    // layer 2: fp8 table, quad-per-edge gather (4 edges/load)
    gemm_kernel<64><<<blocksG, 256, 0, stream>>>(u1h, Wh2, b2, t8);
    agg_kernel<1, 0><<<blocksN64, 256, 0, stream>>>(t8, deg, ell, u2h, nullptr, nullptr, nullptr);
    // layer 3 (no act) + LDS-combined pooling
    gemm_kernel<64><<<blocksG, 256, 0, stream>>>(u2h, Wh3, b3, t8);
    agg_kernel<0, 1><<<blocksN64, 256, 0, stream>>>(t8, deg, ell, nullptr, batch, pooled, cntg);

    head_kernel<<<G, 64, 0, stream>>>(pooled, cntg, Wl, bl, out);
}